// Round 6
// baseline (1068.670 us; speedup 1.0000x reference)
//
#include <hip/hip_runtime.h>
#include <hip/hip_bf16.h>

// Entire file: no FMA contraction — every fl32 mul/add must round separately to
// mirror numpy's SSE/AVX f32 semantics in the argmin-critical path.
#pragma clang fp contract(off)

// ===================================================================================
// Bit-exact replication of the numpy-f32 reference for the argmin path:
//   zp  = np.einsum('bnd,cd->bnc', z, Wq) + bq          (einsum f32 SSE pattern)
//   A   = np.sum(zp*zp, axis=2)                         (pairwise f32, AVX512 npyv)
//   B   = np.sum(emb*emb, axis=1)                       (pairwise f32, AVX512 npyv)
//   M   = np.einsum('bnc,kc->bnk', zp, emb)             (einsum f32 SSE pattern)
//   d   = fl32( fl32(A + B) - 2*M );  argmin first-index
// ===================================================================================

// np.sum pairwise for n=64 contiguous f32, AVX512 npyv path:
// r0 = x[0:16]+x[32:48], r1 = x[16:32]+x[48:64], v = r0+r1, then
// _mm512_reduce_add_ps tree: s_j=v_j+v_{j+8}; t_j=s_j+s_{j+4}; (t0+t2)+(t1+t3)
__device__ __forceinline__ float np_pairwise64_sq(const float* __restrict__ p) {
    float v[16];
#pragma unroll
    for (int j = 0; j < 16; ++j) {
        float x0 = p[j]      * p[j];
        float x1 = p[j + 32] * p[j + 32];
        float x2 = p[j + 16] * p[j + 16];
        float x3 = p[j + 48] * p[j + 48];
        float r0 = x0 + x1;
        float r1 = x2 + x3;
        v[j] = r0 + r1;
    }
    float s[8], t[4];
#pragma unroll
    for (int j = 0; j < 8; ++j) s[j] = v[j] + v[j + 8];
#pragma unroll
    for (int j = 0; j < 4; ++j) t[j] = s[j] + s[j + 4];
    return (t[0] + t[2]) + (t[1] + t[3]);
}

// ---------------- zp = einsum-SSE f32 dot + bq ----------------
// lane j accumulates elements d ≡ j (mod 4) sequentially; reduce (l0+l1)+(l2+l3)
__global__ __launch_bounds__(64) void k_zp_np(const float* __restrict__ z,
                                              const float* __restrict__ Wq,
                                              const float* __restrict__ bq,
                                              float* __restrict__ zp32,
                                              int DIN, int CD) {
    extern __shared__ float zl[];                 // DIN floats
    const int t = blockIdx.x;
    const int tid = threadIdx.x;
    for (int i = tid; i < DIN; i += 64) zl[i] = z[(size_t)t * DIN + i];
    __syncthreads();
    const int main8 = DIN & ~7;                   // SSE unrolled region
    for (int c = tid; c < CD; c += 64) {
        const float* wr = Wq + (size_t)c * DIN;
        float l0 = 0.f, l1 = 0.f, l2 = 0.f, l3 = 0.f;
        for (int m = 0; m < main8; m += 4) {
            l0 += zl[m]     * wr[m];
            l1 += zl[m + 1] * wr[m + 1];
            l2 += zl[m + 2] * wr[m + 2];
            l3 += zl[m + 3] * wr[m + 3];
        }
        float acc = (l0 + l1) + (l2 + l3);
        for (int i = main8; i < DIN; ++i) acc += zl[i] * wr[i];   // np scalar remainder
        zp32[(size_t)t * CD + c] = acc + bq[c];
    }
}

// ---------------- A[t] / B[k]: np pairwise sum of squares (CD==64) ----------------
__global__ __launch_bounds__(256) void k_rowsum2_np(const float* __restrict__ src,
                                                    float* __restrict__ dst,
                                                    int rows) {
    const int r = blockIdx.x * 256 + threadIdx.x;
    if (r >= rows) return;
    dst[r] = np_pairwise64_sq(src + (size_t)r * 64);
}

// generic fallback (CD != 64): scalar 8-accumulator pairwise approximation
__global__ __launch_bounds__(256) void k_rowsum2_gen(const float* __restrict__ src,
                                                     float* __restrict__ dst,
                                                     int rows, int CD) {
    const int r = blockIdx.x * 256 + threadIdx.x;
    if (r >= rows) return;
    const float* p = src + (size_t)r * CD;
    if (CD < 8) {
        float a = 0.f;
        for (int i = 0; i < CD; ++i) a += p[i] * p[i];
        dst[r] = a;
        return;
    }
    float acc[8];
#pragma unroll
    for (int j = 0; j < 8; ++j) acc[j] = p[j] * p[j];
    const int main8 = CD & ~7;
    for (int i = 8; i < main8; i += 8)
#pragma unroll
        for (int j = 0; j < 8; ++j) acc[j] += p[i + j] * p[i + j];
    float res = ((acc[0] + acc[1]) + (acc[2] + acc[3])) + ((acc[4] + acc[5]) + (acc[6] + acc[7]));
    for (int i = main8; i < CD; ++i) res += p[i] * p[i];
    dst[r] = res;
}

// ---------------- exact np-f32 argmin scan (CD==64, K%128==0) ----------------
// 16 tokens/block, 128 codes/tile; thread (tq,cs) handles 4 tokens x 2 codes.
__global__ __launch_bounds__(256) void k_scan_np(const float* __restrict__ emb,
                                                 const float* __restrict__ zp32,
                                                 const float* __restrict__ A32,
                                                 const float* __restrict__ B32,
                                                 int* __restrict__ idx,
                                                 float* __restrict__ out_idx,
                                                 int tokens, int K) {
    constexpr int CD = 64, TK = 128, ES = 68;
    __shared__ float s_emb[TK * ES];
    __shared__ float s_zp[16 * CD];
    __shared__ float s_m[256 * 4];
    __shared__ int   s_j[256 * 4];

    const int tid = threadIdx.x;
    const int tq = tid >> 6;      // token quad 0..3
    const int cs = tid & 63;      // code slot 0..63
    const int tok_base = blockIdx.x * 16;

    for (int i = tid; i < 16 * CD; i += 256) {
        const int t = tok_base + i / CD;
        s_zp[i] = (t < tokens) ? zp32[(size_t)t * CD + (i % CD)] : 0.f;
    }

    float At[4];
#pragma unroll
    for (int i = 0; i < 4; ++i) {
        const int t = tok_base + tq * 4 + i;
        At[i] = (t < tokens) ? A32[t] : 0.f;
    }

    float m1[4];
    int   j1[4];
#pragma unroll
    for (int i = 0; i < 4; ++i) { m1[i] = 3.0e38f; j1[i] = 0; }

    const float* zp_t[4];
#pragma unroll
    for (int i = 0; i < 4; ++i) zp_t[i] = s_zp + (tq * 4 + i) * CD;
    const float* e0p = s_emb + (cs * 2 + 0) * ES;
    const float* e1p = s_emb + (cs * 2 + 1) * ES;

    for (int tile = 0; tile < K / TK; ++tile) {
        __syncthreads();
        const float4* src4 = (const float4*)(emb + (size_t)tile * TK * CD);
        for (int f = tid; f < TK * CD / 4; f += 256) {
            const int kl = f >> 4, c4 = f & 15;
            ((float4*)(s_emb + kl * ES))[c4] = src4[f];
        }
        __syncthreads();

        float l[4][2][4];
#pragma unroll
        for (int i = 0; i < 4; ++i)
#pragma unroll
            for (int s = 0; s < 2; ++s)
#pragma unroll
                for (int j = 0; j < 4; ++j) l[i][s][j] = 0.f;

#pragma unroll
        for (int c4 = 0; c4 < 16; ++c4) {
            const float4 e0 = *(const float4*)(e0p + c4 * 4);
            const float4 e1 = *(const float4*)(e1p + c4 * 4);
#pragma unroll
            for (int i = 0; i < 4; ++i) {
                const float4 p = *(const float4*)(zp_t[i] + c4 * 4);
                l[i][0][0] += p.x * e0.x; l[i][0][1] += p.y * e0.y;
                l[i][0][2] += p.z * e0.z; l[i][0][3] += p.w * e0.w;
                l[i][1][0] += p.x * e1.x; l[i][1][1] += p.y * e1.y;
                l[i][1][2] += p.z * e1.z; l[i][1][3] += p.w * e1.w;
            }
        }
        const int kg0 = tile * TK + cs * 2;
        const float b0 = B32[kg0];
        const float b1 = B32[kg0 + 1];
#pragma unroll
        for (int i = 0; i < 4; ++i) {
            // code kg0: d = fl(fl(A+B) - fl(2*M)), M = (l0+l1)+(l2+l3)
            {
                float M = (l[i][0][0] + l[i][0][1]) + (l[i][0][2] + l[i][0][3]);
                float S = At[i] + b0;
                float d = S - 2.f * M;
                if (d < m1[i]) { m1[i] = d; j1[i] = kg0; }     // strict <: first index
            }
            {
                float M = (l[i][1][0] + l[i][1][1]) + (l[i][1][2] + l[i][1][3]);
                float S = At[i] + b1;
                float d = S - 2.f * M;
                if (d < m1[i]) { m1[i] = d; j1[i] = kg0 + 1; }
            }
        }
    }

#pragma unroll
    for (int i = 0; i < 4; ++i) {
        s_m[tid * 4 + i] = m1[i];
        s_j[tid * 4 + i] = j1[i];
    }
    __syncthreads();

    if (tid < 16) {
        const int t = tok_base + tid;
        if (t < tokens) {
            const int tqq = tid >> 2, ii = tid & 3;
            float gm = 3.0e38f;
            int gj = 0;
            for (int c = 0; c < 64; ++c) {
                const int slot = (tqq * 64 + c) * 4 + ii;
                const float av = s_m[slot];
                const int   aj = s_j[slot];
                if (av < gm || (av == gm && aj < gj)) { gm = av; gj = aj; }
            }
            idx[t] = gj;
            out_idx[t] = (float)gj;
        }
    }
}

// generic exact fallback (any CD%4==0, any K): one block per token
__global__ __launch_bounds__(256) void k_scan_gen(const float* __restrict__ emb,
                                                  const float* __restrict__ zp32,
                                                  const float* __restrict__ A32,
                                                  const float* __restrict__ B32,
                                                  int* __restrict__ idx,
                                                  float* __restrict__ out_idx,
                                                  int K, int CD) {
    extern __shared__ float sm[];
    float* zp = sm;                 // CD
    float* rm = zp + CD;            // 256
    int*   rj = (int*)(rm + 256);   // 256
    const int t = blockIdx.x;
    const int tid = threadIdx.x;
    for (int i = tid; i < CD; i += 256) zp[i] = zp32[(size_t)t * CD + i];
    __syncthreads();
    const float A = A32[t];
    float m1 = 3.0e38f; int j1 = 0;
    const int main8 = CD & ~7;
    for (int k = tid; k < K; k += 256) {
        const float* e = emb + (size_t)k * CD;
        float l0 = 0.f, l1 = 0.f, l2 = 0.f, l3 = 0.f;
        for (int m = 0; m < main8; m += 4) {
            l0 += zp[m]     * e[m];
            l1 += zp[m + 1] * e[m + 1];
            l2 += zp[m + 2] * e[m + 2];
            l3 += zp[m + 3] * e[m + 3];
        }
        float M = (l0 + l1) + (l2 + l3);
        for (int i = main8; i < CD; ++i) M += zp[i] * e[i];
        float S = A + B32[k];
        float d = S - 2.f * M;
        if (d < m1) { m1 = d; j1 = k; }
    }
    rm[tid] = m1; rj[tid] = j1;
    __syncthreads();
    if (tid == 0) {
        float gm = 3.0e38f; int gj = 0;
        for (int s = 0; s < 256; ++s) {
            if (rm[s] < gm || (rm[s] == gm && rj[s] < gj)) { gm = rm[s]; gj = rj[s]; }
        }
        idx[t] = gj;
        out_idx[t] = (float)gj;
    }
}

// ---------------- out = (zp + (emb[idx]-zp)) @ Wp^T + bp  (STE z_q) ----------------
__global__ __launch_bounds__(256) void k_out(const float* __restrict__ emb,
                                             const float* __restrict__ zp32,
                                             const int* __restrict__ idx,
                                             const float* __restrict__ Wp,
                                             const float* __restrict__ bp,
                                             float* __restrict__ out,
                                             int DOUT, int CD) {
    extern __shared__ float zq[];         // CD floats
    const int t = blockIdx.x;
    const int tid = threadIdx.x;
    const int k = idx[t];
    for (int i = tid; i < CD; i += 256) {
        const float zpv = zp32[(size_t)t * CD + i];
        const float df = emb[(size_t)k * CD + i] - zpv;   // fl(e - zp)
        zq[i] = zpv + df;                                 // fl(zp + (e-zp))
    }
    __syncthreads();
    for (int d = tid; d < DOUT; d += 256) {
        const float* w = Wp + (size_t)d * CD;
        float acc = 0.f;
        for (int c = 0; c < CD; ++c) acc += zq[c] * w[c];
        out[(size_t)t * DOUT + d] = acc + bp[d];
    }
}

// ---------------- commit loss = 1.25 * mean(fl(e - zp)^2) ----------------
__global__ __launch_bounds__(256) void k_loss1(const float* __restrict__ zp32,
                                               const float* __restrict__ emb,
                                               const int* __restrict__ idx,
                                               double* __restrict__ part,
                                               long long total, int CD) {
    double acc = 0.0;
    const long long stride = (long long)gridDim.x * 256;
    for (long long e = (long long)blockIdx.x * 256 + threadIdx.x; e < total; e += stride) {
        const long long t = e / CD;
        const int c = (int)(e - t * CD);
        const float df = emb[(size_t)idx[t] * CD + c] - zp32[e];   // fl(e - zp)
        acc += (double)df * (double)df;
    }
    __shared__ double red[256];
    red[threadIdx.x] = acc;
    __syncthreads();
    for (int s = 128; s > 0; s >>= 1) {
        if (threadIdx.x < s) red[threadIdx.x] += red[threadIdx.x + s];
        __syncthreads();
    }
    if (threadIdx.x == 0) part[blockIdx.x] = red[0];
}

__global__ __launch_bounds__(64) void k_loss2(const double* __restrict__ part,
                                              float* __restrict__ out_loss,
                                              double denom) {
    __shared__ double red[64];
    red[threadIdx.x] = part[threadIdx.x];
    __syncthreads();
    for (int s = 32; s > 0; s >>= 1) {
        if (threadIdx.x < s) red[threadIdx.x] += red[threadIdx.x + s];
        __syncthreads();
    }
    if (threadIdx.x == 0)
        *out_loss = (float)(1.25 * red[0] / denom);
}

extern "C" void kernel_launch(void* const* d_in, const int* in_sizes, int n_in,
                              void* d_out, int out_size, void* d_ws, size_t ws_size,
                              hipStream_t stream) {
    const float* z   = (const float*)d_in[0];
    const float* Wq  = (const float*)d_in[1];
    const float* bq  = (const float*)d_in[2];
    const float* emb = (const float*)d_in[3];
    const float* Wp  = (const float*)d_in[4];
    const float* bp  = (const float*)d_in[5];

    const int CD   = in_sizes[2];                        // bq: (CDIM,)
    const int DIN  = in_sizes[1] / CD;                   // Wq: (CDIM, DIN)
    const int DOUT = in_sizes[5];                        // bp: (DOUT,)
    const int K    = in_sizes[3] / CD;                   // emb: (K, CDIM)
    const long long T = (long long)in_sizes[0] / DIN;    // z: (B*N, DIN)

    // d_out is float32: out (T*DOUT) | sample_idxs (T, as float) | commit_loss (1)
    float* out      = (float*)d_out;
    float* out_idx  = out + (size_t)T * DOUT;
    float* out_loss = out_idx + T;

    char* ws = (char*)d_ws;
    size_t off = 0;
    auto carve = [&](size_t bytes) -> char* {
        char* p = ws + off;
        off = (off + bytes + 255) & ~(size_t)255;
        return p;
    };
    float*  zp32 = (float*)carve((size_t)T * CD * 4);
    float*  A32  = (float*)carve((size_t)T * 4);
    float*  B32  = (float*)carve((size_t)K * 4);
    int*    idx  = (int*)carve((size_t)T * 4);
    double* part = (double*)carve(64 * 8);

    k_zp_np<<<dim3((unsigned)T), dim3(64), (size_t)DIN * 4, stream>>>(z, Wq, bq, zp32, DIN, CD);

    if (CD == 64) {
        k_rowsum2_np<<<dim3((unsigned)((T + 255) / 256)), dim3(256), 0, stream>>>(zp32, A32, (int)T);
        k_rowsum2_np<<<dim3((K + 255) / 256), dim3(256), 0, stream>>>(emb, B32, K);
    } else {
        k_rowsum2_gen<<<dim3((unsigned)((T + 255) / 256)), dim3(256), 0, stream>>>(zp32, A32, (int)T, CD);
        k_rowsum2_gen<<<dim3((K + 255) / 256), dim3(256), 0, stream>>>(emb, B32, K, CD);
    }

    if (CD == 64 && K % 128 == 0) {
        k_scan_np<<<dim3((unsigned)((T + 15) / 16)), dim3(256), 0, stream>>>(
            emb, zp32, A32, B32, idx, out_idx, (int)T, K);
    } else {
        const size_t sm = (size_t)CD * 4 + 256 * 4 + 256 * 4;
        k_scan_gen<<<dim3((unsigned)T), dim3(256), sm, stream>>>(
            emb, zp32, A32, B32, idx, out_idx, K, CD);
    }

    k_loss1<<<dim3(64), dim3(256), 0, stream>>>(zp32, emb, idx, part, (long long)T * CD, CD);
    k_loss2<<<dim3(1), dim3(64), 0, stream>>>(part, out_loss, (double)T * CD);
    k_out<<<dim3((unsigned)T), dim3(256), (size_t)CD * 4, stream>>>(emb, zp32, idx, Wp, bp, out, DOUT, CD);
}

// Round 7
// 687.036 us; speedup vs baseline: 1.5555x; 1.5555x over previous
//
#include <hip/hip_runtime.h>
#include <hip/hip_bf16.h>

// ===================================================================================
// Verified (R6, absmax 3e-5): argmin path must bit-replicate numpy-f32:
//   zp  = einsum SSE mod-4 accumulators (l0..l3), reduce (l0+l1)+(l2+l3), + bq
//   A,B = pairwise f32 row-sum-of-squares (AVX512 npyv tree for n=64)
//   d   = fl32( fl32(A + B_k) - fl32(2*M_k) ),  M_k in SSE mod-4 order
//   argmin = strict <, ascending k (first index wins)
// Those kernels carry `#pragma clang fp contract(off)` at function scope.
// k_out / k_loss have loose thresholds -> default contraction (FMA) allowed.
// ===================================================================================

__device__ __forceinline__ float np_pairwise64_sq(const float* __restrict__ p) {
    #pragma clang fp contract(off)
    float v[16];
#pragma unroll
    for (int j = 0; j < 16; ++j) {
        float x0 = p[j]      * p[j];
        float x1 = p[j + 32] * p[j + 32];
        float x2 = p[j + 16] * p[j + 16];
        float x3 = p[j + 48] * p[j + 48];
        float r0 = x0 + x1;
        float r1 = x2 + x3;
        v[j] = r0 + r1;
    }
    float s[8], t[4];
#pragma unroll
    for (int j = 0; j < 8; ++j) s[j] = v[j] + v[j + 8];
#pragma unroll
    for (int j = 0; j < 4; ++j) t[j] = s[j] + s[j + 4];
    return (t[0] + t[2]) + (t[1] + t[3]);
}

// ---------------- zp = einsum-SSE f32 dot + bq (np-exact) ----------------
__global__ __launch_bounds__(64) void k_zp_np(const float* __restrict__ z,
                                              const float* __restrict__ Wq,
                                              const float* __restrict__ bq,
                                              float* __restrict__ zp32,
                                              int DIN, int CD) {
    #pragma clang fp contract(off)
    extern __shared__ float zl[];                 // DIN floats
    const int t = blockIdx.x;
    const int tid = threadIdx.x;
    for (int i = tid; i < DIN; i += 64) zl[i] = z[(size_t)t * DIN + i];
    __syncthreads();
    const int main8 = DIN & ~7;
    for (int c = tid; c < CD; c += 64) {
        const float* wr = Wq + (size_t)c * DIN;
        float l0 = 0.f, l1 = 0.f, l2 = 0.f, l3 = 0.f;
        for (int m = 0; m < main8; m += 4) {
            l0 += zl[m]     * wr[m];
            l1 += zl[m + 1] * wr[m + 1];
            l2 += zl[m + 2] * wr[m + 2];
            l3 += zl[m + 3] * wr[m + 3];
        }
        float acc = (l0 + l1) + (l2 + l3);
        for (int i = main8; i < DIN; ++i) acc += zl[i] * wr[i];
        zp32[(size_t)t * CD + c] = acc + bq[c];
    }
}

// ---------------- A / B: np pairwise sum of squares (CD==64, np-exact) ----------------
__global__ __launch_bounds__(256) void k_rowsum2_np(const float* __restrict__ src,
                                                    float* __restrict__ dst,
                                                    int rows) {
    #pragma clang fp contract(off)
    const int r = blockIdx.x * 256 + threadIdx.x;
    if (r >= rows) return;
    dst[r] = np_pairwise64_sq(src + (size_t)r * 64);
}

__global__ __launch_bounds__(256) void k_rowsum2_gen(const float* __restrict__ src,
                                                     float* __restrict__ dst,
                                                     int rows, int CD) {
    #pragma clang fp contract(off)
    const int r = blockIdx.x * 256 + threadIdx.x;
    if (r >= rows) return;
    const float* p = src + (size_t)r * CD;
    if (CD < 8) {
        float a = 0.f;
        for (int i = 0; i < CD; ++i) a += p[i] * p[i];
        dst[r] = a;
        return;
    }
    float acc[8];
#pragma unroll
    for (int j = 0; j < 8; ++j) acc[j] = p[j] * p[j];
    const int main8 = CD & ~7;
    for (int i = 8; i < main8; i += 8)
#pragma unroll
        for (int j = 0; j < 8; ++j) acc[j] += p[i + j] * p[i + j];
    float res = ((acc[0] + acc[1]) + (acc[2] + acc[3])) + ((acc[4] + acc[5]) + (acc[6] + acc[7]));
    for (int i = main8; i < CD; ++i) res += p[i] * p[i];
    dst[r] = res;
}

// ---------------- np-exact scan v2: lane=token, zp in VGPRs, e broadcast ----------------
// Block: 256 threads = 4 waves; 64 tokens/block (lane = token); wave w handles
// codes [w*32,(w+1)*32) of each 128-code tile. Grid.y = KSPLIT slices of K.
// e-reads are wave-uniform -> LDS broadcast, zero bank conflicts. zp reads are
// registers. Staging is a linear float4 copy (lane i -> banks 4i..4i+3, clean).
#define KSPLIT 8
__global__ __launch_bounds__(256) void k_scan_v2(const float* __restrict__ emb,
                                                 const float* __restrict__ zp32,
                                                 const float* __restrict__ A32,
                                                 const float* __restrict__ B32,
                                                 float* __restrict__ pm,
                                                 int* __restrict__ pj,
                                                 int tokens, int K) {
    #pragma clang fp contract(off)
    __shared__ float s_e[128 * 64];     // 32 KB e-tile, unpadded (broadcast reads)
    __shared__ float s_B[128];

    const int tid  = threadIdx.x;
    const int w    = tid >> 6;          // wave id 0..3 -> code sub-slice
    const int lane = tid & 63;          // token lane
    const int tok  = blockIdx.x * 64 + lane;
    const bool live = tok < tokens;
    const int trd  = live ? tok : 0;
    const int kslice = K / KSPLIT;
    const int kbase  = blockIdx.y * kslice;

    // zp row -> 64 VGPRs (fully unrolled static indexing)
    float zp[64];
    {
        const float4* zsrc = (const float4*)(zp32 + (size_t)trd * 64);
#pragma unroll
        for (int i = 0; i < 16; ++i) {
            float4 v = zsrc[i];
            zp[4*i] = v.x; zp[4*i+1] = v.y; zp[4*i+2] = v.z; zp[4*i+3] = v.w;
        }
    }
    const float A = A32[trd];

    float m1 = 3.0e38f;
    int   j1 = 0x7fffffff;

    for (int t0 = 0; t0 < kslice; t0 += 128) {
        __syncthreads();
        {   // linear conflict-free staging: 8192 floats = 2048 float4 / 256 thr
            const float4* src = (const float4*)(emb + (size_t)(kbase + t0) * 64);
            float4* dst = (float4*)s_e;
#pragma unroll
            for (int i = 0; i < 8; ++i) dst[tid + i * 256] = src[tid + i * 256];
            if (tid < 128) s_B[tid] = B32[kbase + t0 + tid];
        }
        __syncthreads();

        // two codes per iteration for ILP (8 independent accumulator chains)
#pragma unroll 2
        for (int kk = 0; kk < 32; kk += 2) {
            const int k0 = w * 32 + kk;
            const int k1 = k0 + 1;
            const float4* e0 = (const float4*)(s_e + k0 * 64);
            const float4* e1 = (const float4*)(s_e + k1 * 64);
            float a0 = 0.f, a1 = 0.f, a2 = 0.f, a3 = 0.f;
            float b0 = 0.f, b1 = 0.f, b2 = 0.f, b3 = 0.f;
#pragma unroll
            for (int c = 0; c < 16; ++c) {
                const float4 x = e0[c];
                const float4 y = e1[c];
                a0 += zp[4*c]   * x.x;  b0 += zp[4*c]   * y.x;
                a1 += zp[4*c+1] * x.y;  b1 += zp[4*c+1] * y.y;
                a2 += zp[4*c+2] * x.z;  b2 += zp[4*c+2] * y.z;
                a3 += zp[4*c+3] * x.w;  b3 += zp[4*c+3] * y.w;
            }
            const float M0 = (a0 + a1) + (a2 + a3);
            const float M1 = (b0 + b1) + (b2 + b3);
            const float d0 = (A + s_B[k0]) - 2.f * M0;
            const float d1 = (A + s_B[k1]) - 2.f * M1;
            const int kg0 = kbase + t0 + k0;
            // ascending k within thread + strict < == first-index semantics
            if (d0 < m1) { m1 = d0; j1 = kg0; }
            if (d1 < m1) { m1 = d1; j1 = kg0 + 1; }
        }
    }

    if (live) {
        // per-token partial for this K-slice; waves cover disjoint k-sets, so
        // reduce the 4 waves' partials lexicographically via global partials:
        // write per-(slice,wave) -> merge kernel handles all 4*KSPLIT entries.
        const size_t slot = ((size_t)(blockIdx.y * 4 + w)) * tokens + tok;
        pm[slot] = m1;
        pj[slot] = j1;
    }
}

// lex merge of S partials per token: min value, ties -> smallest index
__global__ __launch_bounds__(256) void k_merge(const float* __restrict__ pm,
                                               const int* __restrict__ pj,
                                               int S, int tokens,
                                               int* __restrict__ idx,
                                               float* __restrict__ out_idx) {
    const int t = blockIdx.x * 256 + threadIdx.x;
    if (t >= tokens) return;
    float gm = 3.0e38f;
    int   gj = 0x7fffffff;
    for (int s = 0; s < S; ++s) {
        const float av = pm[(size_t)s * tokens + t];
        const int   aj = pj[(size_t)s * tokens + t];
        if (av < gm || (av == gm && aj < gj)) { gm = av; gj = aj; }
    }
    idx[t] = gj;
    out_idx[t] = (float)gj;
}

// generic exact fallback (any CD%4==0, any K): one block per token
__global__ __launch_bounds__(256) void k_scan_gen(const float* __restrict__ emb,
                                                  const float* __restrict__ zp32,
                                                  const float* __restrict__ A32,
                                                  const float* __restrict__ B32,
                                                  int* __restrict__ idx,
                                                  float* __restrict__ out_idx,
                                                  int K, int CD) {
    #pragma clang fp contract(off)
    extern __shared__ float sm[];
    float* zp = sm;
    float* rm = zp + CD;
    int*   rj = (int*)(rm + 256);
    const int t = blockIdx.x;
    const int tid = threadIdx.x;
    for (int i = tid; i < CD; i += 256) zp[i] = zp32[(size_t)t * CD + i];
    __syncthreads();
    const float A = A32[t];
    float m1 = 3.0e38f; int j1 = 0x7fffffff;
    const int main8 = CD & ~7;
    for (int k = tid; k < K; k += 256) {
        const float* e = emb + (size_t)k * CD;
        float l0 = 0.f, l1 = 0.f, l2 = 0.f, l3 = 0.f;
        for (int m = 0; m < main8; m += 4) {
            l0 += zp[m]     * e[m];
            l1 += zp[m + 1] * e[m + 1];
            l2 += zp[m + 2] * e[m + 2];
            l3 += zp[m + 3] * e[m + 3];
        }
        float M = (l0 + l1) + (l2 + l3);
        for (int i = main8; i < CD; ++i) M += zp[i] * e[i];
        float S = A + B32[k];
        float d = S - 2.f * M;
        if (d < m1) { m1 = d; j1 = k; }
    }
    rm[tid] = m1; rj[tid] = j1;
    __syncthreads();
    if (tid == 0) {
        float gm = 3.0e38f; int gj = 0x7fffffff;
        for (int s = 0; s < 256; ++s) {
            if (rm[s] < gm || (rm[s] == gm && rj[s] < gj)) { gm = rm[s]; gj = rj[s]; }
        }
        idx[t] = gj;
        out_idx[t] = (float)gj;
    }
}

// ---------------- out = (zp + (emb[idx]-zp)) @ Wp^T + bp  (FMA ok, loose thresh) ----
__global__ __launch_bounds__(256) void k_out(const float* __restrict__ emb,
                                             const float* __restrict__ zp32,
                                             const int* __restrict__ idx,
                                             const float* __restrict__ Wp,
                                             const float* __restrict__ bp,
                                             float* __restrict__ out,
                                             int DOUT, int CD) {
    extern __shared__ float zq[];         // CD floats
    const int t = blockIdx.x;
    const int tid = threadIdx.x;
    const int k = idx[t];
    for (int i = tid; i < CD; i += 256) {
        const float zpv = zp32[(size_t)t * CD + i];
        zq[i] = zpv + (emb[(size_t)k * CD + i] - zpv);
    }
    __syncthreads();
    for (int d = tid; d < DOUT; d += 256) {
        const float* w = Wp + (size_t)d * CD;
        float acc = 0.f;
        for (int c = 0; c < CD; ++c) acc += zq[c] * w[c];
        out[(size_t)t * DOUT + d] = acc + bp[d];
    }
}

// ---------------- commit loss = 1.25 * mean(fl(e - zp)^2) ----------------
__global__ __launch_bounds__(256) void k_loss1(const float* __restrict__ zp32,
                                               const float* __restrict__ emb,
                                               const int* __restrict__ idx,
                                               double* __restrict__ part,
                                               long long total, int CD) {
    double acc = 0.0;
    const long long stride = (long long)gridDim.x * 256;
    for (long long e = (long long)blockIdx.x * 256 + threadIdx.x; e < total; e += stride) {
        const long long t = e / CD;
        const int c = (int)(e - t * CD);
        const float df = emb[(size_t)idx[t] * CD + c] - zp32[e];
        acc += (double)df * (double)df;
    }
    __shared__ double red[256];
    red[threadIdx.x] = acc;
    __syncthreads();
    for (int s = 128; s > 0; s >>= 1) {
        if (threadIdx.x < s) red[threadIdx.x] += red[threadIdx.x + s];
        __syncthreads();
    }
    if (threadIdx.x == 0) part[blockIdx.x] = red[0];
}

__global__ __launch_bounds__(64) void k_loss2(const double* __restrict__ part,
                                              float* __restrict__ out_loss,
                                              double denom) {
    __shared__ double red[64];
    red[threadIdx.x] = part[threadIdx.x];
    __syncthreads();
    for (int s = 32; s > 0; s >>= 1) {
        if (threadIdx.x < s) red[threadIdx.x] += red[threadIdx.x + s];
        __syncthreads();
    }
    if (threadIdx.x == 0)
        *out_loss = (float)(1.25 * red[0] / denom);
}

extern "C" void kernel_launch(void* const* d_in, const int* in_sizes, int n_in,
                              void* d_out, int out_size, void* d_ws, size_t ws_size,
                              hipStream_t stream) {
    const float* z   = (const float*)d_in[0];
    const float* Wq  = (const float*)d_in[1];
    const float* bq  = (const float*)d_in[2];
    const float* emb = (const float*)d_in[3];
    const float* Wp  = (const float*)d_in[4];
    const float* bp  = (const float*)d_in[5];

    const int CD   = in_sizes[2];                        // bq: (CDIM,)
    const int DIN  = in_sizes[1] / CD;                   // Wq: (CDIM, DIN)
    const int DOUT = in_sizes[5];                        // bp: (DOUT,)
    const int K    = in_sizes[3] / CD;                   // emb: (K, CDIM)
    const long long T = (long long)in_sizes[0] / DIN;    // z: (B*N, DIN)

    // d_out is float32: out (T*DOUT) | sample_idxs (T, as float) | commit_loss (1)
    float* out      = (float*)d_out;
    float* out_idx  = out + (size_t)T * DOUT;
    float* out_loss = out_idx + T;

    char* ws = (char*)d_ws;
    size_t off = 0;
    auto carve = [&](size_t bytes) -> char* {
        char* p = ws + off;
        off = (off + bytes + 255) & ~(size_t)255;
        return p;
    };
    float*  zp32 = (float*)carve((size_t)T * CD * 4);
    float*  A32  = (float*)carve((size_t)T * 4);
    float*  B32  = (float*)carve((size_t)K * 4);
    int*    idx  = (int*)carve((size_t)T * 4);
    double* part = (double*)carve(128 * 8);
    float*  pm   = (float*)carve((size_t)T * KSPLIT * 4 * 4);   // 4 waves x KSPLIT
    int*    pj   = (int*)carve((size_t)T * KSPLIT * 4 * 4);

    k_zp_np<<<dim3((unsigned)T), dim3(64), (size_t)DIN * 4, stream>>>(z, Wq, bq, zp32, DIN, CD);

    if (CD == 64) {
        k_rowsum2_np<<<dim3((unsigned)((T + 255) / 256)), dim3(256), 0, stream>>>(zp32, A32, (int)T);
        k_rowsum2_np<<<dim3((K + 255) / 256), dim3(256), 0, stream>>>(emb, B32, K);
    } else {
        k_rowsum2_gen<<<dim3((unsigned)((T + 255) / 256)), dim3(256), 0, stream>>>(zp32, A32, (int)T, CD);
        k_rowsum2_gen<<<dim3((K + 255) / 256), dim3(256), 0, stream>>>(emb, B32, K, CD);
    }

    if (CD == 64 && K % (KSPLIT * 128) == 0) {
        dim3 grid((unsigned)((T + 63) / 64), KSPLIT);
        k_scan_v2<<<grid, dim3(256), 0, stream>>>(emb, zp32, A32, B32, pm, pj, (int)T, K);
        k_merge<<<dim3((unsigned)((T + 255) / 256)), dim3(256), 0, stream>>>(
            pm, pj, KSPLIT * 4, (int)T, idx, out_idx);
    } else {
        const size_t sm = (size_t)CD * 4 + 256 * 4 + 256 * 4;
        k_scan_gen<<<dim3((unsigned)T), dim3(256), sm, stream>>>(
            emb, zp32, A32, B32, idx, out_idx, K, CD);
    }

    k_loss1<<<dim3(128), dim3(256), 0, stream>>>(zp32, emb, idx, part, (long long)T * CD, CD);
    k_loss2<<<dim3(1), dim3(64), 0, stream>>>(part, out_loss, (double)T * CD);
    k_out<<<dim3((unsigned)T), dim3(256), (size_t)CD * 4, stream>>>(emb, zp32, idx, Wp, bp, out, DOUT, CD);
}